// Round 12
// baseline (723.570 us; speedup 1.0000x reference)
//
#include <hip/hip_runtime.h>
#include <math.h>

#define NMS_THRESH 0.7f
#define NANCH 36864
#define TOPK 6000
#define NWORDS 94    // ceil(6000/64)
#define POSTK 300
#define MAXCAND 10240

__device__ __forceinline__ float dpp_shr1(float x) {   // lane n <- lane n-1 (0 at 16-lane row start)
    return __int_as_float(__builtin_amdgcn_update_dpp(0, __float_as_int(x), 0x111, 0xF, 0xF, true));
}
__device__ __forceinline__ float dpp_shl1(float x) {   // lane n <- lane n+1 (0 at 16-lane row end)
    return __int_as_float(__builtin_amdgcn_update_dpp(0, __float_as_int(x), 0x101, 0xF, 0xF, true));
}
__device__ __forceinline__ void glds16(const float* g, float* l) {
    __builtin_amdgcn_global_load_lds(
        (const __attribute__((address_space(1))) void*)g,
        (__attribute__((address_space(3))) void*)l, 16, 0, 0);
}

// ---------------- conv 3x3 + bias + relu, batch 0 only ----------------
// (r11-validated: 295 us, VALUBusy 94%, VGPR 88, no spill — UNCHANGED)
__global__ __launch_bounds__(256, 2)
void k_conv(const float* __restrict__ feat, const float* __restrict__ W,
            const float* __restrict__ bias, float* __restrict__ tout)
{
    __shared__ float sF[2 * 6168];    // 49,344 B
    __shared__ float sW[16 * 148];    //  9,472 B   (58,816 total)

    const int blk = blockIdx.x;
    const int ct  = blk & 31;
    const int yt  = blk >> 5;
    const int cob = ct << 4;
    const int y0  = yt << 2;
    const int tid = threadIdx.x;
    const int lane = tid & 63;
    const int wid = __builtin_amdgcn_readfirstlane(tid >> 6);  // 0..3 uniform
    const int cwo = wid << 2;
    const int co0 = cob + cwo;
    const int ly = lane >> 4;             // row 0..3
    const int lx = (lane & 15) << 2;      // col 0..60 step 4

    const int ci_g = (wid << 2) + ly;
    const int x_g  = lx;

    const int sci = tid >> 4, sco = tid & 15;
    const float* wsrc = W + (size_t)(cob + sco) * 4608 + sci * 9;

    float acc[4][4];
    #pragma unroll
    for (int i = 0; i < 4; ++i)
        #pragma unroll
        for (int j = 0; j < 4; ++j) acc[i][j] = 0.f;

    if (yt == 0)
        for (int q = tid; q < 1028; q += 256) { sF[q] = 0.f; sF[6168 + q] = 0.f; }
    if (yt == 15)
        for (int q = tid; q < 1028; q += 256) { sF[5140 + q] = 0.f; sF[6168 + 5140 + q] = 0.f; }
    float wreg[9];
    {
        #pragma unroll
        for (int s = 0; s < 6; ++s) {
            int gy = y0 - 1 + s;                       // uniform per block
            if (gy >= 0 && gy < 64) {
                const float* ga = feat + ((size_t)ci_g << 12) + (gy << 6) + x_g;
                glds16(ga, &sF[s * 1028 + (wid << 8)]);
            }
        }
        #pragma unroll
        for (int t = 0; t < 9; ++t) wreg[t] = wsrc[t];
    }
    __syncthreads();

#define LOADG(F, WQ, g) do {                                              \
        const int _ci = (g) / 3, _ky = (g) % 3;                           \
        F = *(const float4*)&fb[(ly + _ky) * 1028 + _ci * 64 + lx];       \
        *(float4*)&WQ[0] = *(const float4*)&sW[_ci * 148 + _ky * 48 + cwo];        \
        *(float4*)&WQ[4] = *(const float4*)&sW[_ci * 148 + _ky * 48 + 16 + cwo];   \
        *(float4*)&WQ[8] = *(const float4*)&sW[_ci * 148 + _ky * 48 + 32 + cwo];   \
    } while (0)

#define COMP(F, WQ) do {                                                  \
        float fr[6];                                                      \
        fr[0] = dpp_shr1(F.w);                                            \
        fr[1] = F.x; fr[2] = F.y; fr[3] = F.z; fr[4] = F.w;               \
        fr[5] = dpp_shl1(F.x);                                            \
        _Pragma("unroll")                                                 \
        for (int kx = 0; kx < 3; ++kx)                                    \
            _Pragma("unroll")                                             \
            for (int i = 0; i < 4; ++i)                                   \
                _Pragma("unroll")                                         \
                for (int j = 0; j < 4; ++j)                               \
                    acc[i][j] = fmaf(fr[i + kx], WQ[kx * 4 + j], acc[i][j]); \
    } while (0)

    int p = 0;
    for (int cc = 0; cc < 32; ++cc) {
        const bool more = cc < 31;
        #pragma unroll
        for (int t = 0; t < 9; ++t)
            sW[sci * 148 + t * 16 + sco] = wreg[t];
        __syncthreads();
        float wregN[9];
        if (more) {
            const float* fsrc = feat + ((size_t)(cc + 1) << 16);
            const int db = (p ^ 1) * 6168 + (wid << 8);
            #pragma unroll
            for (int s = 0; s < 6; ++s) {
                int gy = y0 - 1 + s;
                if (gy >= 0 && gy < 64) {
                    const float* ga = fsrc + ((size_t)ci_g << 12) + (gy << 6) + x_g;
                    glds16(ga, &sF[db + s * 1028]);
                }
            }
            const float* wp = wsrc + (size_t)(cc + 1) * 144;
            #pragma unroll
            for (int t = 0; t < 9; ++t) wregN[t] = wp[t];
        }
        {
            const float* fb = sF + p * 6168;
            float4 fA, fB; float wqA[12], wqB[12];
            LOADG(fA, wqA, 0);
            LOADG(fB, wqB, 1);
            #pragma unroll
            for (int gp = 0; gp < 24; ++gp) {
                COMP(fA, wqA);
                if (2 * gp + 2 < 48) LOADG(fA, wqA, 2 * gp + 2);
                COMP(fB, wqB);
                if (2 * gp + 3 < 48) LOADG(fB, wqB, 2 * gp + 3);
            }
        }
        if (more) {
            #pragma unroll
            for (int t = 0; t < 9; ++t) wreg[t] = wregN[t];
        }
        __syncthreads();
        p ^= 1;
    }
#undef LOADG
#undef COMP

    const int y = y0 + ly;
    #pragma unroll
    for (int j = 0; j < 4; ++j) {
        const float bv = bias[co0 + j];
        float4 o;
        o.x = fmaxf(acc[0][j] + bv, 0.f);
        o.y = fmaxf(acc[1][j] + bv, 0.f);
        o.z = fmaxf(acc[2][j] + bv, 0.f);
        o.w = fmaxf(acc[3][j] + bv, 0.f);
        *(float4*)&tout[((size_t)(co0 + j) << 12) + (y << 6) + lx] = o;
    }
}

// ---------------- head-weight repack: wall[ci][48] ----------------
__global__ void k_wall(const float* __restrict__ cls_w, const float* __restrict__ reg_w,
                       float* __restrict__ wall)
{
    int idx = blockIdx.x * 256 + threadIdx.x;
    if (idx >= 512 * 48) return;
    int ci = idx / 48, ch = idx - ci * 48;
    float v = 0.f;
    if (ch < 9) v = cls_w[ch * 512 + ci];
    else if (ch < 45) v = reg_w[(ch - 9) * 512 + ci];
    wall[idx] = v;
}

// ---------------- fused 1x1 heads + decode + hist ----------------
// grid 16 x 256; thread = 1 px, 45 accumulators (compile-time indexed).
// t read EXACTLY once (8.4 MB vs 377 MB before); heads buffer eliminated.
// ci ascending fmaf -> logits bitwise == previous rounds (absmax 0 lineage).
// Unrolled a-loop makes anchor f64 math compile-time (same IEEE values).
__global__ __launch_bounds__(256, 1)
void k_headdec(const float* __restrict__ t, const float* __restrict__ wall,
               const float* __restrict__ cls_b, const float* __restrict__ reg_b,
               float* __restrict__ score, float* __restrict__ validf,
               float* __restrict__ box, unsigned* __restrict__ hist)
{
    __shared__ unsigned lh[4096];
    const int tid = threadIdx.x;
    for (int q = tid; q < 4096; q += 256) lh[q] = 0u;
    __syncthreads();

    const int px = blockIdx.x * 256 + tid;
    float acc[45];
    #pragma unroll
    for (int ch = 0; ch < 9; ++ch) acc[ch] = cls_b[ch];
    #pragma unroll
    for (int ch = 0; ch < 36; ++ch) acc[9 + ch] = reg_b[ch];

    #pragma unroll 4
    for (int ci = 0; ci < 512; ++ci) {
        float v = t[((size_t)ci << 12) + px];
        const float* wrow = wall + ci * 48;          // uniform -> s_loads
        #pragma unroll
        for (int ch = 0; ch < 45; ++ch)
            acc[ch] = fmaf(v, wrow[ch], acc[ch]);
    }

    const int yq = px >> 6, xq = px & 63;
    const float sx = xq * 16.0f + 8.0f;
    const float sy = yq * 16.0f + 8.0f;

    #pragma unroll
    for (int a = 0; a < 9; ++a) {
        const double scl[3] = {128.0, 256.0, 512.0};
        const double rat[3] = {0.5, 1.0, 2.0};
        double s = scl[a / 3], r = rat[a % 3];       // compile-time after unroll
        float bw = (float)(s * sqrt(1.0 / r) * 0.5);
        float bh = (float)(s * sqrt(r) * 0.5);
        float a0 = sx - bw, a1 = sy - bh, a2 = sx + bw, a3 = sy + bh;
        float wa = a2 - a0, ha = a3 - a1;
        float cx = a0 + 0.5f * wa, cy = a1 + 0.5f * ha;
        float logit = acc[a];
        float dx = acc[9 + 4 * a], dy = acc[10 + 4 * a];
        float dw = fminf(acc[11 + 4 * a], 4.135166556742356f);
        float dh = fminf(acc[12 + 4 * a], 4.135166556742356f);
        float pcx = dx * wa + cx, pcy = dy * ha + cy;
        float pw = expf(dw) * wa, ph = expf(dh) * ha;
        float x1 = pcx - 0.5f * pw, y1 = pcy - 0.5f * ph;
        float x2 = pcx + 0.5f * pw, y2 = pcy + 0.5f * ph;
        x1 = fminf(fmaxf(x1, 0.f), 1024.f); y1 = fminf(fmaxf(y1, 0.f), 1024.f);
        x2 = fminf(fmaxf(x2, 0.f), 1024.f); y2 = fminf(fmaxf(y2, 0.f), 1024.f);
        float wv = x2 - x1, hv = y2 - y1;
        float sc = 1.f / (1.f + expf(-logit));
        const int idx = px * 9 + a;
        score[idx]  = sc;
        validf[idx] = (wv >= 1.f && hv >= 1.f) ? 1.f : 0.f;
        float4 bx; bx.x = x1; bx.y = y1; bx.z = x2; bx.w = y2;
        *(float4*)&box[idx * 4] = bx;
        atomicAdd(&lh[__float_as_uint(sc) >> 19], 1u);
    }
    __syncthreads();
    for (int q = tid; q < 4096; q += 256) if (lh[q]) atomicAdd(&hist[q], lh[q]);
}

// ---------------- top-k cutoff machinery ----------------
__global__ void k_zero(unsigned* __restrict__ p) {
    int i = blockIdx.x * 256 + threadIdx.x;
    if (i < 8448) p[i] = 0u;   // hist + pad + meta
}

// fused: cut1 (coarse bin) + hist2 (refine, LDS) + cut2 (final cutoff). 1 block.
__global__ void k_cut(const unsigned* __restrict__ hist, const float* __restrict__ score,
                      unsigned* __restrict__ meta)
{
    __shared__ unsigned hh[4096];
    __shared__ unsigned gs[256];
    __shared__ unsigned sbin, sabove;
    const int tid = threadIdx.x;
    for (int q = tid; q < 4096; q += 256) hh[q] = hist[q];
    __syncthreads();
    unsigned s = 0;
    #pragma unroll
    for (int k = 0; k < 16; ++k) s += hh[tid * 16 + k];
    gs[tid] = s;
    __syncthreads();
    if (tid == 0) {
        unsigned cum = 0;
        for (int g = 255; g >= 0; --g) {
            if (cum + gs[g] >= (unsigned)TOPK) {
                for (int b = g * 16 + 15; b >= g * 16; --b) {
                    if (cum + hh[b] >= (unsigned)TOPK) { sbin = (unsigned)b; sabove = cum; break; }
                    cum += hh[b];
                }
                break;
            }
            cum += gs[g];
        }
    }
    __syncthreads();
    const unsigned bin1 = sbin;
    for (int q = tid; q < 4096; q += 256) hh[q] = 0u;
    __syncthreads();
    for (int idx = tid; idx < NANCH; idx += 256) {
        unsigned bits = __float_as_uint(score[idx]);
        if ((bits >> 19) == bin1) atomicAdd(&hh[(bits >> 7) & 0xFFFu], 1u);
    }
    __syncthreads();
    s = 0;
    #pragma unroll
    for (int k = 0; k < 16; ++k) s += hh[tid * 16 + k];
    gs[tid] = s;
    __syncthreads();
    if (tid == 0) {
        unsigned cum = sabove;
        unsigned cut = bin1 << 19;
        for (int g = 255; g >= 0; --g) {
            if (cum + gs[g] >= (unsigned)TOPK) {
                for (int b = g * 16 + 15; b >= g * 16; --b) {
                    cum += hh[b];
                    if (cum >= (unsigned)TOPK) { cut = (bin1 << 19) | ((unsigned)b << 7); break; }
                }
                break;
            }
            cum += gs[g];
        }
        meta[0] = cut;
    }
}

__global__ void k_compact(const float* __restrict__ score, unsigned* __restrict__ meta,
                          int* __restrict__ cand, float* __restrict__ cscore) {
    int idx = blockIdx.x * 256 + threadIdx.x;
    unsigned bits = __float_as_uint(score[idx]);
    if (bits >= meta[0]) {
        unsigned pos = atomicAdd(&meta[1], 1u);
        if (pos < (unsigned)MAXCAND) {
            cand[pos] = idx;
            cscore[pos] = __uint_as_float(bits);
        }
    }
}

// ---------------- exact ranks, candidate-vs-candidate only ----------------
__global__ __launch_bounds__(256, 4)
void k_rank(const float* __restrict__ score, const float* __restrict__ validf,
            const float* __restrict__ box, const unsigned* __restrict__ meta,
            const int* __restrict__ cand, const float* __restrict__ cscore,
            float* __restrict__ score6, float* __restrict__ sc6,
            float* __restrict__ box6)
{
    __shared__ int pc[8][32];
    const int tid = threadIdx.x;
    const int il = tid & 31, js = tid >> 5;
    unsigned ncand = meta[1]; if (ncand > (unsigned)MAXCAND) ncand = MAXCAND;
    const int c = blockIdx.x * 32 + il;
    int i = -1; float si = 0.f;
    if (c < (int)ncand) { i = cand[c]; si = cscore[c]; }
    int cnt = 0;
    {
        const float4* cs4 = (const float4*)cscore;
        const int4*   cd4 = (const int4*)cand;
        const int q0 = js * 320;                // 8 splits x 320 float4 = 10240
        for (int q = 0; q < 320; ++q) {
            float4 v = cs4[q0 + q];
            int4   w = cd4[q0 + q];
            cnt += (v.x > si) || (v.x == si && w.x < i);
            cnt += (v.y > si) || (v.y == si && w.y < i);
            cnt += (v.z > si) || (v.z == si && w.z < i);
            cnt += (v.w > si) || (v.w == si && w.w < i);
        }
    }
    pc[js][il] = cnt;
    __syncthreads();
    if (js == 0 && i >= 0) {
        int rank = 0;
        #pragma unroll
        for (int q = 0; q < 8; ++q) rank += pc[q][il];
        if (rank < TOPK) {
            score6[rank] = si;
            sc6[rank] = (validf[i] != 0.f) ? si : -INFINITY;
            box6[rank * 4 + 0] = box[i * 4 + 0];
            box6[rank * 4 + 1] = box[i * 4 + 1];
            box6[rank * 4 + 2] = box[i * 4 + 2];
            box6[rank * 4 + 3] = box[i * 4 + 3];
        }
    }
}

// ---------------- fused NMS: kept boxes in LDS, IoU on the fly ----------------
__global__ __launch_bounds__(512)
void k_nms(const float* __restrict__ sc6, const float* __restrict__ score6,
           const float* __restrict__ box6, float* __restrict__ out)
{
    __shared__ float kx1[POSTK], ky1[POSTK], kx2[POSTK], ky2[POSTK], kar[POSTK];
    __shared__ int kidx[POSTK];
    __shared__ unsigned long long pOR[8];
    __shared__ int kcnt_s;
    const int tid = threadIdx.x, lane = tid & 63, wv = tid >> 6;

    if (tid == 0) kcnt_s = 0;
    int i0 = lane;
    float cx1 = box6[i0 * 4 + 0], cy1 = box6[i0 * 4 + 1];
    float cx2 = box6[i0 * 4 + 2], cy2 = box6[i0 * 4 + 3];
    float csc = sc6[i0];
    __syncthreads();

    for (int b = 0; b < NWORDS; ++b) {
        float nx1 = 0.f, ny1 = 0.f, nx2 = 0.f, ny2 = 0.f, nsc = -INFINITY;
        if (b + 1 < NWORDS) {
            int ni = (b + 1) * 64 + lane; if (ni >= TOPK) ni = TOPK - 1;
            nx1 = box6[ni * 4 + 0]; ny1 = box6[ni * 4 + 1];
            nx2 = box6[ni * 4 + 2]; ny2 = box6[ni * 4 + 3];
            nsc = sc6[ni];
        }
        const int i = b * 64 + lane;
        const bool v = (i < TOPK) && (csc > -INFINITY);
        const float ar = (cx2 - cx1) * (cy2 - cy1);
        const int kc = kcnt_s;
        bool dead = false;
        for (int j = wv; j < kc; j += 8) {
            float xl = fmaxf(kx1[j], cx1), yt = fmaxf(ky1[j], cy1);
            float xr = fminf(kx2[j], cx2), yb = fminf(ky2[j], cy2);
            float inter = fmaxf(xr - xl, 0.f) * fmaxf(yb - yt, 0.f);
            float iou = inter / (kar[j] + ar - inter);
            dead = dead || (iou > NMS_THRESH);
        }
        pOR[wv] = __ballot(dead);
        __syncthreads();
        if (wv == 0) {
            unsigned long long supp = pOR[0] | pOR[1] | pOR[2] | pOR[3]
                                    | pOR[4] | pOR[5] | pOR[6] | pOR[7];
            unsigned long long validb = __ballot(v);
            unsigned long long cand2 = validb & ~supp;
            int kc2 = kc;
            while (cand2 != 0ull && kc2 < POSTK) {
                int rr = __builtin_ctzll(cand2);
                float rx1 = __shfl(cx1, rr, 64), ry1 = __shfl(cy1, rr, 64);
                float rx2 = __shfl(cx2, rr, 64), ry2 = __shfl(cy2, rr, 64);
                float rar = __shfl(ar, rr, 64);
                if (lane == 0) {
                    kx1[kc2] = rx1; ky1[kc2] = ry1;
                    kx2[kc2] = rx2; ky2[kc2] = ry2;
                    kar[kc2] = rar; kidx[kc2] = b * 64 + rr;
                }
                float xl = fmaxf(rx1, cx1), yt = fmaxf(ry1, cy1);
                float xr = fminf(rx2, cx2), yb = fminf(ry2, cy2);
                float inter = fmaxf(xr - xl, 0.f) * fmaxf(yb - yt, 0.f);
                float iou = inter / (rar + ar - inter);
                unsigned long long sm = __ballot(iou > NMS_THRESH) | (1ull << rr);
                cand2 &= ~sm;
                ++kc2;
            }
            if (lane == 0) kcnt_s = kc2;
        }
        __syncthreads();
        if (kcnt_s >= POSTK) break;
        cx1 = nx1; cy1 = ny1; cx2 = nx2; cy2 = ny2; csc = nsc;
    }

    const int kc = kcnt_s;
    for (int n = tid; n < POSTK; n += 512) {
        float o0 = 0.f, o1 = 0.f, o2 = 0.f, o3 = 0.f, o4 = 0.f;
        if (n < kc) {
            int i = kidx[n];
            o0 = box6[i * 4 + 0]; o1 = box6[i * 4 + 1];
            o2 = box6[i * 4 + 2]; o3 = box6[i * 4 + 3];
            o4 = score6[i];
        }
        out[n * 5 + 0] = o0; out[n * 5 + 1] = o1; out[n * 5 + 2] = o2;
        out[n * 5 + 3] = o3; out[n * 5 + 4] = o4;
    }
}

extern "C" void kernel_launch(void* const* d_in, const int* in_sizes, int n_in,
                              void* d_out, int out_size, void* d_ws, size_t ws_size,
                              hipStream_t stream)
{
    (void)in_sizes; (void)n_in; (void)out_size; (void)ws_size;
    const float* feat   = (const float*)d_in[1];   // (8,512,64,64) -> batch 0 only
    const float* conv_w = (const float*)d_in[2];
    const float* conv_b = (const float*)d_in[3];
    const float* cls_w  = (const float*)d_in[4];
    const float* cls_b  = (const float*)d_in[5];
    const float* reg_w  = (const float*)d_in[6];
    const float* reg_b  = (const float*)d_in[7];

    char* ws = (char*)d_ws;
    float*    t      = (float*)(ws + 0);          // 8,388,608 B (dead after k_headdec)
    float*    wall   = (float*)(ws + 8388608);    //    98,304 B
    unsigned* hist   = (unsigned*)(ws + 9125888); //    16,384 B
    unsigned* meta   = (unsigned*)(ws + 9158656); // [0]=cut [1]=ncand
    int*      cand   = (int*)(ws + 9158720);      //    40,960 B
    float*    cscore = (float*)(ws + 9199680);    //    40,960 B
    float*    score  = (float*)(ws + 9240640);    //   147,456 B
    float*    validf = (float*)(ws + 9388096);    //   147,456 B
    float*    box    = (float*)(ws + 9535552);    //   589,824 B
    float*    score6 = (float*)(ws + 10125376);   //    24,576 B
    float*    sc6    = (float*)(ws + 10149952);   //    24,576 B
    float*    box6   = (float*)(ws + 10174528);   //    96,000 B (end 10,270,528)

    k_zero   <<<33,   256, 0, stream>>>(hist);
    k_wall   <<<96,   256, 0, stream>>>(cls_w, reg_w, wall);
    k_conv   <<<512,  256, 0, stream>>>(feat, conv_w, conv_b, t);
    k_headdec<<<16,   256, 0, stream>>>(t, wall, cls_b, reg_b, score, validf, box, hist);
    k_cut    <<<1,    256, 0, stream>>>(hist, score, meta);
    k_compact<<<144,  256, 0, stream>>>(score, meta, cand, cscore);
    k_rank   <<<320,  256, 0, stream>>>(score, validf, box, meta, cand, cscore, score6, sc6, box6);
    k_nms    <<<1,    512, 0, stream>>>(sc6, score6, box6, (float*)d_out);
}

// Round 13
// 513.940 us; speedup vs baseline: 1.4079x; 1.4079x over previous
//
#include <hip/hip_runtime.h>
#include <math.h>

#define NMS_THRESH 0.7f
#define NANCH 36864
#define TOPK 6000
#define NWORDS 94    // ceil(6000/64)
#define POSTK 300
#define MAXCAND 10240

__device__ __forceinline__ float dpp_shr1(float x) {   // lane n <- lane n-1 (0 at 16-lane row start)
    return __int_as_float(__builtin_amdgcn_update_dpp(0, __float_as_int(x), 0x111, 0xF, 0xF, true));
}
__device__ __forceinline__ float dpp_shl1(float x) {   // lane n <- lane n+1 (0 at 16-lane row end)
    return __int_as_float(__builtin_amdgcn_update_dpp(0, __float_as_int(x), 0x101, 0xF, 0xF, true));
}
__device__ __forceinline__ void glds16(const float* g, float* l) {
    __builtin_amdgcn_global_load_lds(
        (const __attribute__((address_space(1))) void*)g,
        (__attribute__((address_space(3))) void*)l, 16, 0, 0);
}

// ---------------- conv 3x3 + bias + relu, batch 0 only ----------------
// grid 512 = y_tile(16) x co_tile(32); block 128 (2 waves); 2 blocks/CU.
// block: 16 co x (4 rows x 64 cols); wave w owns co [cob+8w,+8); thread 4px x 8co.
// 96 FMA per (ci,ky) group vs ~14 overhead issue slots (r11: 48 vs ~14) ->
// issue-bound time drops ~30%. Feat LDS [2][6 slabs][1028] via glds16 (zero
// staging VGPRs); weights LDS [16ci][148] broadcast b128; 2-slot (ci,ky)
// pipeline; x-edges via DPP (bit-exact zeros). 1 wave/SIMD: latency covered by
// pipeline + 2 staggered blocks/CU. VGPR unconstrained (4 waves/CU -> any
// alloc <= 512 is free); launch_bounds(128,1) avoids r9's spill cap.
__global__ __launch_bounds__(128, 1)
void k_conv(const float* __restrict__ feat, const float* __restrict__ W,
            const float* __restrict__ bias, float* __restrict__ tout)
{
    __shared__ float sF[2 * 6168];    // 49,344 B
    __shared__ float sW[16 * 148];    //  9,472 B   (58,816 total, 2 blocks/CU)

    const int blk = blockIdx.x;
    const int ct  = blk & 31;             // co-tile 0..31 (fastest -> L2 slab reuse)
    const int yt  = blk >> 5;             // y-tile 0..15
    const int cob = ct << 4;              // 16 co per block
    const int y0  = yt << 2;
    const int tid = threadIdx.x;          // 0..127
    const int lane = tid & 63;
    const int wid = __builtin_amdgcn_readfirstlane(tid >> 6);  // 0..1 uniform
    const int cwo = wid << 3;             // 0 or 8
    const int co0 = cob + cwo;
    const int ly = lane >> 4;             // row 0..3
    const int lx = (lane & 15) << 2;      // col 0..60 step 4

    // weight staging: thread (sci=tid>>3, scp=tid&7) loads 9 taps of co pair {2scp,2scp+1}
    const int sci = tid >> 3, scp = tid & 7;
    const float* wsrc0 = W + (size_t)(cob + 2 * scp) * 4608 + sci * 9;
    const float* wsrc1 = wsrc0 + 4608;

    float acc[4][8];
    #pragma unroll
    for (int i = 0; i < 4; ++i)
        #pragma unroll
        for (int j = 0; j < 8; ++j) acc[i][j] = 0.f;

    // prologue: zero boundary slabs (both buffers), stage tile 0 -> buf 0
    if (yt == 0)
        for (int q = tid; q < 1028; q += 128) { sF[q] = 0.f; sF[6168 + q] = 0.f; }
    if (yt == 15)
        for (int q = tid; q < 1028; q += 128) { sF[5140 + q] = 0.f; sF[6168 + 5140 + q] = 0.f; }
    float wreg[18];
    {
        // 12 glds per wave: u -> slab s = wid*3 + u/4, part = u&3.
        // lane l covers slab floats part*256 + l*4 (ci = part*4 + l/16, x = (l%16)*4)
        #pragma unroll
        for (int u = 0; u < 12; ++u) {
            const int s = wid * 3 + (u >> 2), part = u & 3;
            int gy = y0 - 1 + s;
            if (gy >= 0 && gy < 64) {
                const float* ga = feat + (((size_t)(part * 4 + ly)) << 12) + (gy << 6) + lx;
                glds16(ga, &sF[s * 1028 + part * 256]);
            }
        }
        #pragma unroll
        for (int t = 0; t < 9; ++t) { wreg[t] = wsrc0[t]; wreg[9 + t] = wsrc1[t]; }
    }
    __syncthreads();   // drains glds (tile 0 complete) + zeros visible

#define LOADG(F, WQ, g) do {                                              \
        const int _ci = (g) / 3, _ky = (g) % 3;                           \
        F = *(const float4*)&fb[(ly + _ky) * 1028 + _ci * 64 + lx];       \
        const float* _wb = sW + _ci * 148 + _ky * 48 + cwo;               \
        *(float4*)&WQ[0]  = *(const float4*)(_wb);                        \
        *(float4*)&WQ[4]  = *(const float4*)(_wb + 4);                    \
        *(float4*)&WQ[8]  = *(const float4*)(_wb + 16);                   \
        *(float4*)&WQ[12] = *(const float4*)(_wb + 20);                   \
        *(float4*)&WQ[16] = *(const float4*)(_wb + 32);                   \
        *(float4*)&WQ[20] = *(const float4*)(_wb + 36);                   \
    } while (0)

#define COMP(F, WQ) do {                                                  \
        float fr[6];                                                      \
        fr[0] = dpp_shr1(F.w);                                            \
        fr[1] = F.x; fr[2] = F.y; fr[3] = F.z; fr[4] = F.w;               \
        fr[5] = dpp_shl1(F.x);                                            \
        _Pragma("unroll")                                                 \
        for (int kx = 0; kx < 3; ++kx)                                    \
            _Pragma("unroll")                                             \
            for (int i = 0; i < 4; ++i)                                   \
                _Pragma("unroll")                                         \
                for (int j = 0; j < 8; ++j)                               \
                    acc[i][j] = fmaf(fr[i + kx], WQ[kx * 8 + j], acc[i][j]); \
    } while (0)

    int p = 0;
    for (int cc = 0; cc < 32; ++cc) {
        const bool more = cc < 31;
        // A: write weights(cc) to sW (float2 = co pair)
        #pragma unroll
        for (int t = 0; t < 9; ++t) {
            float2 wp2; wp2.x = wreg[t]; wp2.y = wreg[9 + t];
            *(float2*)&sW[sci * 148 + t * 16 + 2 * scp] = wp2;
        }
        __syncthreads();   // sW(cc) visible; sF[p] complete (prev barrier drained glds)
        // C: issue async feat(cc+1)->sF[p^1] + weight(cc+1) loads, then compute.
        float wregN[18];
        if (more) {
            const float* fsrc = feat + ((size_t)(cc + 1) << 16);
            const int db = (p ^ 1) * 6168;
            #pragma unroll
            for (int u = 0; u < 12; ++u) {
                const int s = wid * 3 + (u >> 2), part = u & 3;
                int gy = y0 - 1 + s;
                if (gy >= 0 && gy < 64) {
                    const float* ga = fsrc + (((size_t)(part * 4 + ly)) << 12) + (gy << 6) + lx;
                    glds16(ga, &sF[db + s * 1028 + part * 256]);
                }
            }
            const float* wp0 = wsrc0 + (size_t)(cc + 1) * 144;
            const float* wp1 = wsrc1 + (size_t)(cc + 1) * 144;
            #pragma unroll
            for (int t = 0; t < 9; ++t) { wregN[t] = wp0[t]; wregN[9 + t] = wp1[t]; }
        }
        {
            const float* fb = sF + p * 6168;
            float4 fA, fB; float wqA[24], wqB[24];
            LOADG(fA, wqA, 0);
            LOADG(fB, wqB, 1);
            #pragma unroll
            for (int gp = 0; gp < 24; ++gp) {
                COMP(fA, wqA);
                if (2 * gp + 2 < 48) LOADG(fA, wqA, 2 * gp + 2);
                COMP(fB, wqB);
                if (2 * gp + 3 < 48) LOADG(fB, wqB, 2 * gp + 3);
            }
        }
        if (more) {
            #pragma unroll
            for (int t = 0; t < 18; ++t) wreg[t] = wregN[t];
        }
        __syncthreads();   // drains glds: sF[p^1] ready; sW reusable
        p ^= 1;
    }
#undef LOADG
#undef COMP

    const int y = y0 + ly;
    #pragma unroll
    for (int j = 0; j < 8; ++j) {
        const float bv = bias[co0 + j];
        float4 o;
        o.x = fmaxf(acc[0][j] + bv, 0.f);
        o.y = fmaxf(acc[1][j] + bv, 0.f);
        o.z = fmaxf(acc[2][j] + bv, 0.f);
        o.w = fmaxf(acc[3][j] + bv, 0.f);
        *(float4*)&tout[((size_t)(co0 + j) << 12) + (y << 6) + lx] = o;
    }
}

// ---------------- 1x1 heads: wave = 64 px of one channel ----------------
// px-tile-major: 45 consecutive blocks share the same t rows -> L2 hits
__global__ __launch_bounds__(64)
void k_heads(const float* __restrict__ t, const float* __restrict__ cls_w,
             const float* __restrict__ cls_b, const float* __restrict__ reg_w,
             const float* __restrict__ reg_b, float* __restrict__ heads)
{
    const int bid = blockIdx.x;
    const int ch = bid % 45;                  // uniform
    const int pt = bid / 45;
    const int px = (pt << 6) + threadIdx.x;
    const float* wp; float bv;
    if (ch < 9) { wp = cls_w + ch * 512;       bv = cls_b[ch]; }
    else        { wp = reg_w + (ch - 9) * 512; bv = reg_b[ch - 9]; }
    float acc = bv;
    #pragma unroll 8
    for (int ci = 0; ci < 512; ++ci)
        acc = fmaf(t[((size_t)ci << 12) + px], wp[ci], acc);
    heads[((size_t)ch << 12) + px] = acc;
}

// ---------------- decode + sigmoid + clip + validity + hist1 (fused) ----------------
__global__ void k_decode(const float* __restrict__ heads,
                         float* __restrict__ score, float* __restrict__ validf,
                         float* __restrict__ box, unsigned* __restrict__ hist)
{
    __shared__ unsigned lh[4096];
    const int tid = threadIdx.x;
    for (int q = tid; q < 4096; q += 256) lh[q] = 0u;
    __syncthreads();

    int idx = blockIdx.x * 256 + tid;
    int p = idx / 9, a = idx - p * 9;
    int yq = p >> 6, xq = p & 63;
    const double scl[3] = {128.0, 256.0, 512.0};
    const double rat[3] = {0.5, 1.0, 2.0};
    double s = scl[a / 3], r = rat[a % 3];
    float bw = (float)(s * sqrt(1.0 / r) * 0.5);
    float bh = (float)(s * sqrt(r) * 0.5);
    float sx = xq * 16.0f + 8.0f;
    float sy = yq * 16.0f + 8.0f;
    float a0 = sx - bw, a1 = sy - bh, a2 = sx + bw, a3 = sy + bh;
    float wa = a2 - a0, ha = a3 - a1;
    float cx = a0 + 0.5f * wa, cy = a1 + 0.5f * ha;
    float logit = heads[(size_t)a * 4096 + p];
    float dx = heads[(size_t)(9  + 4 * a) * 4096 + p];
    float dy = heads[(size_t)(10 + 4 * a) * 4096 + p];
    float dw = fminf(heads[(size_t)(11 + 4 * a) * 4096 + p], 4.135166556742356f);
    float dh = fminf(heads[(size_t)(12 + 4 * a) * 4096 + p], 4.135166556742356f);
    float pcx = dx * wa + cx, pcy = dy * ha + cy;
    float pw = expf(dw) * wa, ph = expf(dh) * ha;
    float x1 = pcx - 0.5f * pw, y1 = pcy - 0.5f * ph;
    float x2 = pcx + 0.5f * pw, y2 = pcy + 0.5f * ph;
    x1 = fminf(fmaxf(x1, 0.f), 1024.f); y1 = fminf(fmaxf(y1, 0.f), 1024.f);
    x2 = fminf(fmaxf(x2, 0.f), 1024.f); y2 = fminf(fmaxf(y2, 0.f), 1024.f);
    float wv = x2 - x1, hv = y2 - y1;
    float sc = 1.f / (1.f + expf(-logit));
    score[idx]  = sc;
    validf[idx] = (wv >= 1.f && hv >= 1.f) ? 1.f : 0.f;
    box[idx * 4 + 0] = x1; box[idx * 4 + 1] = y1;
    box[idx * 4 + 2] = x2; box[idx * 4 + 3] = y2;

    atomicAdd(&lh[__float_as_uint(sc) >> 19], 1u);
    __syncthreads();
    for (int q = tid; q < 4096; q += 256) if (lh[q]) atomicAdd(&hist[q], lh[q]);
}

// ---------------- top-k cutoff machinery ----------------
__global__ void k_zero(unsigned* __restrict__ p) {
    int i = blockIdx.x * 256 + threadIdx.x;
    if (i < 8448) p[i] = 0u;   // hist + pad + meta
}

// fused: cut1 (coarse bin) + hist2 (refine, LDS) + cut2 (final cutoff). 1 block.
__global__ void k_cut(const unsigned* __restrict__ hist, const float* __restrict__ score,
                      unsigned* __restrict__ meta)
{
    __shared__ unsigned hh[4096];
    __shared__ unsigned gs[256];
    __shared__ unsigned sbin, sabove;
    const int tid = threadIdx.x;
    for (int q = tid; q < 4096; q += 256) hh[q] = hist[q];
    __syncthreads();
    unsigned s = 0;
    #pragma unroll
    for (int k = 0; k < 16; ++k) s += hh[tid * 16 + k];
    gs[tid] = s;
    __syncthreads();
    if (tid == 0) {
        unsigned cum = 0;
        for (int g = 255; g >= 0; --g) {
            if (cum + gs[g] >= (unsigned)TOPK) {
                for (int b = g * 16 + 15; b >= g * 16; --b) {
                    if (cum + hh[b] >= (unsigned)TOPK) { sbin = (unsigned)b; sabove = cum; break; }
                    cum += hh[b];
                }
                break;
            }
            cum += gs[g];
        }
    }
    __syncthreads();
    const unsigned bin1 = sbin;
    for (int q = tid; q < 4096; q += 256) hh[q] = 0u;
    __syncthreads();
    for (int idx = tid; idx < NANCH; idx += 256) {
        unsigned bits = __float_as_uint(score[idx]);
        if ((bits >> 19) == bin1) atomicAdd(&hh[(bits >> 7) & 0xFFFu], 1u);
    }
    __syncthreads();
    s = 0;
    #pragma unroll
    for (int k = 0; k < 16; ++k) s += hh[tid * 16 + k];
    gs[tid] = s;
    __syncthreads();
    if (tid == 0) {
        unsigned cum = sabove;
        unsigned cut = bin1 << 19;
        for (int g = 255; g >= 0; --g) {
            if (cum + gs[g] >= (unsigned)TOPK) {
                for (int b = g * 16 + 15; b >= g * 16; --b) {
                    cum += hh[b];
                    if (cum >= (unsigned)TOPK) { cut = (bin1 << 19) | ((unsigned)b << 7); break; }
                }
                break;
            }
            cum += gs[g];
        }
        meta[0] = cut;
    }
}

__global__ void k_compact(const float* __restrict__ score, unsigned* __restrict__ meta,
                          int* __restrict__ cand, float* __restrict__ cscore) {
    int idx = blockIdx.x * 256 + threadIdx.x;
    unsigned bits = __float_as_uint(score[idx]);
    if (bits >= meta[0]) {
        unsigned pos = atomicAdd(&meta[1], 1u);
        if (pos < (unsigned)MAXCAND) {
            cand[pos] = idx;
            cscore[pos] = __uint_as_float(bits);
        }
    }
}

// ---------------- exact ranks, candidate-vs-candidate only ----------------
__global__ __launch_bounds__(256, 4)
void k_rank(const float* __restrict__ score, const float* __restrict__ validf,
            const float* __restrict__ box, const unsigned* __restrict__ meta,
            const int* __restrict__ cand, const float* __restrict__ cscore,
            float* __restrict__ score6, float* __restrict__ sc6,
            float* __restrict__ box6)
{
    __shared__ int pc[8][32];
    const int tid = threadIdx.x;
    const int il = tid & 31, js = tid >> 5;
    unsigned ncand = meta[1]; if (ncand > (unsigned)MAXCAND) ncand = MAXCAND;
    const int c = blockIdx.x * 32 + il;
    int i = -1; float si = 0.f;
    if (c < (int)ncand) { i = cand[c]; si = cscore[c]; }
    int cnt = 0;
    {
        const float4* cs4 = (const float4*)cscore;
        const int4*   cd4 = (const int4*)cand;
        const int q0 = js * 320;                // 8 splits x 320 float4 = 10240
        for (int q = 0; q < 320; ++q) {
            float4 v = cs4[q0 + q];
            int4   w = cd4[q0 + q];
            cnt += (v.x > si) || (v.x == si && w.x < i);
            cnt += (v.y > si) || (v.y == si && w.y < i);
            cnt += (v.z > si) || (v.z == si && w.z < i);
            cnt += (v.w > si) || (v.w == si && w.w < i);
        }
    }
    pc[js][il] = cnt;
    __syncthreads();
    if (js == 0 && i >= 0) {
        int rank = 0;
        #pragma unroll
        for (int q = 0; q < 8; ++q) rank += pc[q][il];
        if (rank < TOPK) {
            score6[rank] = si;
            sc6[rank] = (validf[i] != 0.f) ? si : -INFINITY;
            box6[rank * 4 + 0] = box[i * 4 + 0];
            box6[rank * 4 + 1] = box[i * 4 + 1];
            box6[rank * 4 + 2] = box[i * 4 + 2];
            box6[rank * 4 + 3] = box[i * 4 + 3];
        }
    }
}

// ---------------- fused NMS: kept boxes in LDS, IoU on the fly ----------------
__global__ __launch_bounds__(512)
void k_nms(const float* __restrict__ sc6, const float* __restrict__ score6,
           const float* __restrict__ box6, float* __restrict__ out)
{
    __shared__ float kx1[POSTK], ky1[POSTK], kx2[POSTK], ky2[POSTK], kar[POSTK];
    __shared__ int kidx[POSTK];
    __shared__ unsigned long long pOR[8];
    __shared__ int kcnt_s;
    const int tid = threadIdx.x, lane = tid & 63, wv = tid >> 6;

    if (tid == 0) kcnt_s = 0;
    int i0 = lane;
    float cx1 = box6[i0 * 4 + 0], cy1 = box6[i0 * 4 + 1];
    float cx2 = box6[i0 * 4 + 2], cy2 = box6[i0 * 4 + 3];
    float csc = sc6[i0];
    __syncthreads();

    for (int b = 0; b < NWORDS; ++b) {
        float nx1 = 0.f, ny1 = 0.f, nx2 = 0.f, ny2 = 0.f, nsc = -INFINITY;
        if (b + 1 < NWORDS) {
            int ni = (b + 1) * 64 + lane; if (ni >= TOPK) ni = TOPK - 1;
            nx1 = box6[ni * 4 + 0]; ny1 = box6[ni * 4 + 1];
            nx2 = box6[ni * 4 + 2]; ny2 = box6[ni * 4 + 3];
            nsc = sc6[ni];
        }
        const int i = b * 64 + lane;
        const bool v = (i < TOPK) && (csc > -INFINITY);
        const float ar = (cx2 - cx1) * (cy2 - cy1);
        const int kc = kcnt_s;
        bool dead = false;
        for (int j = wv; j < kc; j += 8) {
            float xl = fmaxf(kx1[j], cx1), yt = fmaxf(ky1[j], cy1);
            float xr = fminf(kx2[j], cx2), yb = fminf(ky2[j], cy2);
            float inter = fmaxf(xr - xl, 0.f) * fmaxf(yb - yt, 0.f);
            float iou = inter / (kar[j] + ar - inter);
            dead = dead || (iou > NMS_THRESH);
        }
        pOR[wv] = __ballot(dead);
        __syncthreads();
        if (wv == 0) {
            unsigned long long supp = pOR[0] | pOR[1] | pOR[2] | pOR[3]
                                    | pOR[4] | pOR[5] | pOR[6] | pOR[7];
            unsigned long long validb = __ballot(v);
            unsigned long long cand2 = validb & ~supp;
            int kc2 = kc;
            while (cand2 != 0ull && kc2 < POSTK) {
                int rr = __builtin_ctzll(cand2);
                float rx1 = __shfl(cx1, rr, 64), ry1 = __shfl(cy1, rr, 64);
                float rx2 = __shfl(cx2, rr, 64), ry2 = __shfl(cy2, rr, 64);
                float rar = __shfl(ar, rr, 64);
                if (lane == 0) {
                    kx1[kc2] = rx1; ky1[kc2] = ry1;
                    kx2[kc2] = rx2; ky2[kc2] = ry2;
                    kar[kc2] = rar; kidx[kc2] = b * 64 + rr;
                }
                float xl = fmaxf(rx1, cx1), yt = fmaxf(ry1, cy1);
                float xr = fminf(rx2, cx2), yb = fminf(ry2, cy2);
                float inter = fmaxf(xr - xl, 0.f) * fmaxf(yb - yt, 0.f);
                float iou = inter / (rar + ar - inter);
                unsigned long long sm = __ballot(iou > NMS_THRESH) | (1ull << rr);
                cand2 &= ~sm;
                ++kc2;
            }
            if (lane == 0) kcnt_s = kc2;
        }
        __syncthreads();
        if (kcnt_s >= POSTK) break;
        cx1 = nx1; cy1 = ny1; cx2 = nx2; cy2 = ny2; csc = nsc;
    }

    const int kc = kcnt_s;
    for (int n = tid; n < POSTK; n += 512) {
        float o0 = 0.f, o1 = 0.f, o2 = 0.f, o3 = 0.f, o4 = 0.f;
        if (n < kc) {
            int i = kidx[n];
            o0 = box6[i * 4 + 0]; o1 = box6[i * 4 + 1];
            o2 = box6[i * 4 + 2]; o3 = box6[i * 4 + 3];
            o4 = score6[i];
        }
        out[n * 5 + 0] = o0; out[n * 5 + 1] = o1; out[n * 5 + 2] = o2;
        out[n * 5 + 3] = o3; out[n * 5 + 4] = o4;
    }
}

extern "C" void kernel_launch(void* const* d_in, const int* in_sizes, int n_in,
                              void* d_out, int out_size, void* d_ws, size_t ws_size,
                              hipStream_t stream)
{
    (void)in_sizes; (void)n_in; (void)out_size; (void)ws_size;
    const float* feat   = (const float*)d_in[1];   // (8,512,64,64) -> batch 0 only
    const float* conv_w = (const float*)d_in[2];
    const float* conv_b = (const float*)d_in[3];
    const float* cls_w  = (const float*)d_in[4];
    const float* cls_b  = (const float*)d_in[5];
    const float* reg_w  = (const float*)d_in[6];
    const float* reg_b  = (const float*)d_in[7];

    char* ws = (char*)d_ws;
    float*    t      = (float*)(ws + 0);          // 8,388,608 B (dead after k_heads)
    float*    heads  = (float*)(ws + 8388608);    //   737,280 B
    unsigned* hist   = (unsigned*)(ws + 9125888); //    16,384 B
    unsigned* meta   = (unsigned*)(ws + 9158656); // [0]=cut [1]=ncand
    int*      cand   = (int*)(ws + 9158720);      //    40,960 B
    float*    cscore = (float*)(ws + 9199680);    //    40,960 B
    float*    score  = (float*)(ws + 9240640);    //   147,456 B
    float*    validf = (float*)(ws + 9388096);    //   147,456 B
    float*    box    = (float*)(ws + 9535552);    //   589,824 B
    float*    score6 = (float*)(ws + 10125376);   //    24,576 B
    float*    sc6    = (float*)(ws + 10149952);   //    24,576 B
    float*    box6   = (float*)(ws + 10174528);   //    96,000 B (end 10,270,528)

    k_zero   <<<33,   256, 0, stream>>>(hist);
    k_conv   <<<512,  128, 0, stream>>>(feat, conv_w, conv_b, t);
    k_heads  <<<2880, 64,  0, stream>>>(t, cls_w, cls_b, reg_w, reg_b, heads);
    k_decode <<<144,  256, 0, stream>>>(heads, score, validf, box, hist);
    k_cut    <<<1,    256, 0, stream>>>(hist, score, meta);
    k_compact<<<144,  256, 0, stream>>>(score, meta, cand, cscore);
    k_rank   <<<320,  256, 0, stream>>>(score, validf, box, meta, cand, cscore, score6, sc6, box6);
    k_nms    <<<1,    512, 0, stream>>>(sc6, score6, box6, (float*)d_out);
}